// Round 1
// baseline (1181.601 us; speedup 1.0000x reference)
//
#include <hip/hip_runtime.h>

#define NNODES 50000
#define NEDGES 800000
#define NNODE_DICT 10000
#define NEDGE_DICT 100
#define EMB 128
#define HID 32
#define HEADS 4
#define DD 128            // HID*HEADS
#define SLOPE 0.2f
#define LN_EPS 1e-5f

// ---- monotonic float<->uint encoding for atomicMax on floats ----
__device__ __forceinline__ unsigned enc_f(float f) {
    unsigned u = __float_as_uint(f);
    return (u & 0x80000000u) ? ~u : (u | 0x80000000u);
}
__device__ __forceinline__ float dec_f(unsigned u) {
    return (u & 0x80000000u) ? __uint_as_float(u & 0x7FFFFFFFu)
                             : __uint_as_float(~u);
}

// ---- Kernel A: node dict transform: h_dict = node_emb @ w_W + b; s_i/s_j per row ----
__global__ void node_dict_kernel(const float* __restrict__ node_emb,
                                 const float* __restrict__ w_W,
                                 const float* __restrict__ w_b,
                                 const float* __restrict__ attn,
                                 float* __restrict__ h_dict,
                                 float* __restrict__ s_i_d,
                                 float* __restrict__ s_j_d) {
    __shared__ float a_row[EMB];
    int row = blockIdx.x;
    int col = threadIdx.x;      // 128 threads
    a_row[col] = node_emb[row * EMB + col];
    __syncthreads();
    float acc = 0.f;
    #pragma unroll 8
    for (int k = 0; k < EMB; ++k) acc += a_row[k] * w_W[k * DD + col];
    acc += w_b[col];
    h_dict[row * DD + col] = acc;

    int head = col >> 5, f = col & 31;
    float pi = acc * attn[head * 96 + f];        // a_i
    float pj = acc * attn[head * 96 + 32 + f];   // a_j
    #pragma unroll
    for (int off = 16; off > 0; off >>= 1) {     // reduce within 32-lane head groups
        pi += __shfl_down(pi, off);
        pj += __shfl_down(pj, off);
    }
    if ((col & 31) == 0) {
        s_i_d[row * HEADS + head] = pi;
        s_j_d[row * HEADS + head] = pj;
    }
}

// ---- Kernel B: edge dict transform + s_e + LayerNorm(eh) per dict row ----
__global__ void edge_dict_kernel(const float* __restrict__ edge_emb,
                                 const float* __restrict__ ew_W,
                                 const float* __restrict__ ew_b,
                                 const float* __restrict__ attn,
                                 const float* __restrict__ gamma,
                                 const float* __restrict__ beta,
                                 float* __restrict__ eh_dict,
                                 float* __restrict__ eh2_dict,
                                 float* __restrict__ s_e_d) {
    __shared__ float a_row[EMB];
    __shared__ float red[4];
    int row = blockIdx.x;
    int col = threadIdx.x;
    a_row[col] = edge_emb[row * EMB + col];
    __syncthreads();
    float acc = 0.f;
    #pragma unroll 8
    for (int k = 0; k < EMB; ++k) acc += a_row[k] * ew_W[k * DD + col];
    acc += ew_b[col];
    eh_dict[row * DD + col] = acc;

    int head = col >> 5, f = col & 31;
    float pe = acc * attn[head * 96 + 64 + f];   // a_e
    #pragma unroll
    for (int off = 16; off > 0; off >>= 1) pe += __shfl_down(pe, off);
    if ((col & 31) == 0) s_e_d[row * HEADS + head] = pe;

    // LayerNorm over the 128 cols of this row
    float s = acc, s2 = acc * acc;
    #pragma unroll
    for (int off = 32; off > 0; off >>= 1) {
        s  += __shfl_down(s, off);
        s2 += __shfl_down(s2, off);
    }
    int wid = col >> 6;
    if ((col & 63) == 0) { red[wid * 2] = s; red[wid * 2 + 1] = s2; }
    __syncthreads();
    s = red[0] + red[2];
    s2 = red[1] + red[3];
    float mu = s * (1.f / DD);
    float var = s2 * (1.f / DD) - mu * mu;
    float r = rsqrtf(var + LN_EPS);
    eh2_dict[row * DD + col] = (acc - mu) * r * gamma[col] + beta[col];
}

// ---- Pass A: eij + segment max (one thread per edge, 4 heads) ----
__global__ void edge_pass_a(const int* __restrict__ edge_index,
                            const int* __restrict__ node_features,
                            const int* __restrict__ edge_features,
                            const float* __restrict__ s_i_d,
                            const float* __restrict__ s_j_d,
                            const float* __restrict__ s_e_d,
                            float* __restrict__ eij,
                            unsigned* __restrict__ m_enc) {
    int e = blockIdx.x * blockDim.x + threadIdx.x;
    if (e >= NEDGES) return;
    int tgt = edge_index[e];
    int src = edge_index[NEDGES + e];
    int nt = node_features[tgt];
    int ns = node_features[src];
    int ee = edge_features[e];
    float4 si = *(const float4*)(s_i_d + nt * 4);
    float4 sj = *(const float4*)(s_j_d + ns * 4);
    float4 se = *(const float4*)(s_e_d + ee * 4);
    float v[4] = { si.x + sj.x + se.x, si.y + sj.y + se.y,
                   si.z + sj.z + se.z, si.w + sj.w + se.w };
    #pragma unroll
    for (int h = 0; h < 4; ++h) {
        float s = v[h];
        s = s > 0.f ? s : SLOPE * s;
        v[h] = s;
        atomicMax(m_enc + tgt * 4 + h, enc_f(s));
    }
    *(float4*)(eij + e * 4) = make_float4(v[0], v[1], v[2], v[3]);
}

// ---- Pass B: ex = exp(eij - m[tgt]); denom += ex (in-place overwrite eij->ex) ----
__global__ void edge_pass_b(const int* __restrict__ edge_index,
                            const unsigned* __restrict__ m_enc,
                            float* __restrict__ exbuf,
                            float* __restrict__ denom) {
    int e = blockIdx.x * blockDim.x + threadIdx.x;
    if (e >= NEDGES) return;
    int tgt = edge_index[e];
    float4 ev = *(const float4*)(exbuf + e * 4);
    uint4 me = *(const uint4*)(m_enc + tgt * 4);
    float e0 = __expf(ev.x - dec_f(me.x));
    float e1 = __expf(ev.y - dec_f(me.y));
    float e2 = __expf(ev.z - dec_f(me.z));
    float e3 = __expf(ev.w - dec_f(me.w));
    *(float4*)(exbuf + e * 4) = make_float4(e0, e1, e2, e3);
    atomicAdd(denom + tgt * 4 + 0, e0);
    atomicAdd(denom + tgt * 4 + 1, e1);
    atomicAdd(denom + tgt * 4 + 2, e2);
    atomicAdd(denom + tgt * 4 + 3, e3);
}

// ---- Pass C: message scatter: out[tgt] += alpha * h_dict[nf[src]] (128 thr/edge) ----
__global__ void edge_pass_c(const int* __restrict__ edge_index,
                            const int* __restrict__ node_features,
                            const float* __restrict__ exbuf,
                            const float* __restrict__ denom,
                            const float* __restrict__ h_dict,
                            float* __restrict__ out_acc) {
    int t = blockIdx.x * blockDim.x + threadIdx.x;
    int e = t >> 7;
    int col = t & 127;
    if (e >= NEDGES) return;
    int tgt = edge_index[e];
    int src = edge_index[NEDGES + e];
    int ns = node_features[src];
    int h = col >> 5;
    float alpha = exbuf[e * 4 + h] / denom[tgt * 4 + h];
    float val = alpha * h_dict[ns * DD + col];
    atomicAdd(out_acc + tgt * DD + col, val);
}

// ---- Node finalize: out = LayerNorm(msg_sum + h) ----
__global__ void node_final_kernel(const int* __restrict__ node_features,
                                  const float* __restrict__ h_dict,
                                  const float* __restrict__ gamma,
                                  const float* __restrict__ beta,
                                  float* __restrict__ out) {
    __shared__ float red[4];
    int n = blockIdx.x;
    int col = threadIdx.x;
    float v = out[n * DD + col] + h_dict[node_features[n] * DD + col];
    float s = v, s2 = v * v;
    #pragma unroll
    for (int off = 32; off > 0; off >>= 1) {
        s  += __shfl_down(s, off);
        s2 += __shfl_down(s2, off);
    }
    int wid = col >> 6;
    if ((col & 63) == 0) { red[wid * 2] = s; red[wid * 2 + 1] = s2; }
    __syncthreads();
    s = red[0] + red[2];
    s2 = red[1] + red[3];
    float mu = s * (1.f / DD);
    float var = s2 * (1.f / DD) - mu * mu;
    float r = rsqrtf(var + LN_EPS);
    out[n * DD + col] = (v - mu) * r * gamma[col] + beta[col];
}

// ---- Edge output: eh2[e] = eh2_dict[edge_features[e]] (float4 gather-write) ----
__global__ void edge_out_kernel(const int* __restrict__ edge_features,
                                const float4* __restrict__ eh2_dict4,
                                float4* __restrict__ out4) {
    int t = blockIdx.x * blockDim.x + threadIdx.x;   // 25.6M threads
    int e = t >> 5;                                  // 32 float4 per row
    int j = t & 31;
    if (e >= NEDGES) return;
    int ee = edge_features[e];
    out4[(size_t)t] = eh2_dict4[ee * 32 + j];
}

extern "C" void kernel_launch(void* const* d_in, const int* in_sizes, int n_in,
                              void* d_out, int out_size, void* d_ws, size_t ws_size,
                              hipStream_t stream) {
    const int*   node_features = (const int*)d_in[0];
    const int*   edge_features = (const int*)d_in[1];
    const int*   edge_index    = (const int*)d_in[2];
    const float* node_emb      = (const float*)d_in[3];
    const float* edge_emb      = (const float*)d_in[4];
    const float* w_W           = (const float*)d_in[5];
    const float* w_b           = (const float*)d_in[6];
    const float* ew_W          = (const float*)d_in[7];
    const float* ew_b          = (const float*)d_in[8];
    const float* attn          = (const float*)d_in[9];
    const float* gamma         = (const float*)d_in[10];
    const float* beta          = (const float*)d_in[11];

    float* out_nodes = (float*)d_out;                                  // 50000*128
    float* out_edges = (float*)d_out + (size_t)NNODES * DD;            // 800000*128

    // workspace layout (all counts multiples of 4 floats -> 16B aligned)
    char* w = (char*)d_ws;
    float*    h_dict   = (float*)w;    w += (size_t)NNODE_DICT * DD * 4;   // 5.12 MB
    float*    s_i_d    = (float*)w;    w += (size_t)NNODE_DICT * 4 * 4;
    float*    s_j_d    = (float*)w;    w += (size_t)NNODE_DICT * 4 * 4;
    float*    eh_dict  = (float*)w;    w += (size_t)NEDGE_DICT * DD * 4;
    float*    eh2_dict = (float*)w;    w += (size_t)NEDGE_DICT * DD * 4;
    float*    s_e_d    = (float*)w;    w += (size_t)NEDGE_DICT * 4 * 4;
    unsigned* m_enc    = (unsigned*)w; w += (size_t)NNODES * 4 * 4;        // 0.8 MB
    float*    denom    = (float*)w;    w += (size_t)NNODES * 4 * 4;        // 0.8 MB
    float*    exbuf    = (float*)w;    w += (size_t)NEDGES * 4 * 4;        // 12.8 MB

    // zero the accumulators (enc(x) > 0 for all finite x, so 0 is the max-identity)
    hipMemsetAsync(m_enc, 0, (size_t)NNODES * 4 * 4, stream);
    hipMemsetAsync(denom, 0, (size_t)NNODES * 4 * 4, stream);
    hipMemsetAsync(out_nodes, 0, (size_t)NNODES * DD * 4, stream);

    node_dict_kernel<<<NNODE_DICT, 128, 0, stream>>>(node_emb, w_W, w_b, attn,
                                                     h_dict, s_i_d, s_j_d);
    edge_dict_kernel<<<NEDGE_DICT, 128, 0, stream>>>(edge_emb, ew_W, ew_b, attn,
                                                     gamma, beta,
                                                     eh_dict, eh2_dict, s_e_d);
    edge_pass_a<<<(NEDGES + 255) / 256, 256, 0, stream>>>(edge_index, node_features,
                                                          edge_features, s_i_d, s_j_d,
                                                          s_e_d, exbuf, m_enc);
    edge_pass_b<<<(NEDGES + 255) / 256, 256, 0, stream>>>(edge_index, m_enc,
                                                          exbuf, denom);
    edge_pass_c<<<(NEDGES * 128) / 256, 256, 0, stream>>>(edge_index, node_features,
                                                          exbuf, denom, h_dict,
                                                          out_nodes);
    node_final_kernel<<<NNODES, 128, 0, stream>>>(node_features, h_dict,
                                                  gamma, beta, out_nodes);
    edge_out_kernel<<<(NEDGES * 32 + 255) / 256, 256, 0, stream>>>(edge_features,
                                                                   (const float4*)eh2_dict,
                                                                   (float4*)out_edges);
}

// Round 3
// 684.486 us; speedup vs baseline: 1.7263x; 1.7263x over previous
//
#include <hip/hip_runtime.h>

#define NNODES 50000
#define NEDGES 800000
#define NNODE_DICT 10000
#define NEDGE_DICT 100
#define EMB 128
#define HID 32
#define HEADS 4
#define DD 128            // HID*HEADS
#define SLOPE 0.2f
#define LN_EPS 1e-5f
#define NEG_BIG -3.0e38f

typedef float vfloat4 __attribute__((ext_vector_type(4)));

// ---- Kernel A: node dict transform: h_dict = node_emb @ w_W + b; s_i/s_j per row ----
__global__ void node_dict_kernel(const float* __restrict__ node_emb,
                                 const float* __restrict__ w_W,
                                 const float* __restrict__ w_b,
                                 const float* __restrict__ attn,
                                 float* __restrict__ h_dict,
                                 float* __restrict__ s_i_d,
                                 float* __restrict__ s_j_d) {
    __shared__ float a_row[EMB];
    int row = blockIdx.x;
    int col = threadIdx.x;      // 128 threads
    a_row[col] = node_emb[row * EMB + col];
    __syncthreads();
    float acc = 0.f;
    #pragma unroll 8
    for (int k = 0; k < EMB; ++k) acc += a_row[k] * w_W[k * DD + col];
    acc += w_b[col];
    h_dict[row * DD + col] = acc;

    int head = col >> 5, f = col & 31;
    float pi = acc * attn[head * 96 + f];        // a_i
    float pj = acc * attn[head * 96 + 32 + f];   // a_j
    #pragma unroll
    for (int off = 16; off > 0; off >>= 1) {     // reduce within 32-lane head groups
        pi += __shfl_down(pi, off);
        pj += __shfl_down(pj, off);
    }
    if ((col & 31) == 0) {
        s_i_d[row * HEADS + head] = pi;
        s_j_d[row * HEADS + head] = pj;
    }
}

// ---- Kernel B: edge dict transform + s_e + LayerNorm(eh) per dict row ----
__global__ void edge_dict_kernel(const float* __restrict__ edge_emb,
                                 const float* __restrict__ ew_W,
                                 const float* __restrict__ ew_b,
                                 const float* __restrict__ attn,
                                 const float* __restrict__ gamma,
                                 const float* __restrict__ beta,
                                 float* __restrict__ eh2_dict,
                                 float* __restrict__ s_e_d) {
    __shared__ float a_row[EMB];
    __shared__ float red[4];
    int row = blockIdx.x;
    int col = threadIdx.x;
    a_row[col] = edge_emb[row * EMB + col];
    __syncthreads();
    float acc = 0.f;
    #pragma unroll 8
    for (int k = 0; k < EMB; ++k) acc += a_row[k] * ew_W[k * DD + col];
    acc += ew_b[col];

    int head = col >> 5, f = col & 31;
    float pe = acc * attn[head * 96 + 64 + f];   // a_e
    #pragma unroll
    for (int off = 16; off > 0; off >>= 1) pe += __shfl_down(pe, off);
    if ((col & 31) == 0) s_e_d[row * HEADS + head] = pe;

    // LayerNorm over the 128 cols of this row
    float s = acc, s2 = acc * acc;
    #pragma unroll
    for (int off = 32; off > 0; off >>= 1) {
        s  += __shfl_down(s, off);
        s2 += __shfl_down(s2, off);
    }
    int wid = col >> 6;
    if ((col & 63) == 0) { red[wid * 2] = s; red[wid * 2 + 1] = s2; }
    __syncthreads();
    s = red[0] + red[2];
    s2 = red[1] + red[3];
    float mu = s * (1.f / DD);
    float var = s2 * (1.f / DD) - mu * mu;
    float r = rsqrtf(var + LN_EPS);
    eh2_dict[row * DD + col] = (acc - mu) * r * gamma[col] + beta[col];
}

// ---- CSR build step 1: degree count ----
__global__ void count_kernel(const int* __restrict__ edge_index,
                             int* __restrict__ counts) {
    int e = blockIdx.x * blockDim.x + threadIdx.x;
    if (e < NEDGES) atomicAdd(&counts[edge_index[e]], 1);
}

// ---- CSR build step 2: exclusive scan of 50000 counts (1 block, 1024 thr) ----
__global__ __launch_bounds__(1024) void scan_kernel(const int* __restrict__ counts,
                                                    int* __restrict__ offsets,
                                                    int* __restrict__ cursor) {
    __shared__ int wsum[16], wexcl[16];
    __shared__ int chunktot;
    int tid = threadIdx.x;
    int lane = tid & 63, wid = tid >> 6;
    int carry = 0;
    for (int base = 0; base < NNODES; base += 1024) {
        int i = base + tid;
        int v = (i < NNODES) ? counts[i] : 0;
        // wave inclusive scan
        int incl = v;
        #pragma unroll
        for (int o = 1; o < 64; o <<= 1) {
            int t = __shfl_up(incl, o);
            if (lane >= o) incl += t;
        }
        if (lane == 63) wsum[wid] = incl;
        __syncthreads();
        if (tid < 16) {
            int w = wsum[tid];
            int iw = w;
            #pragma unroll
            for (int o = 1; o < 16; o <<= 1) {
                int t = __shfl_up(iw, o);
                if (tid >= o) iw += t;
            }
            wexcl[tid] = iw - w;
            if (tid == 15) chunktot = iw;
        }
        __syncthreads();
        int ex = carry + wexcl[wid] + incl - v;
        if (i < NNODES) { offsets[i] = ex; cursor[i] = ex; }
        carry += chunktot;
        __syncthreads();   // protect wsum/wexcl/chunktot for next chunk
    }
    if (tid == 0) offsets[NNODES] = carry;
}

// ---- CSR build step 3: scatter edges into CSR order, precomputing eij ----
__global__ void scatter_kernel(const int* __restrict__ edge_index,
                               const int* __restrict__ node_features,
                               const int* __restrict__ edge_features,
                               const float4* __restrict__ s_i_d,
                               const float4* __restrict__ s_j_d,
                               const float4* __restrict__ s_e_d,
                               int* __restrict__ cursor,
                               float4* __restrict__ csr_eij,
                               int* __restrict__ csr_ns) {
    int e = blockIdx.x * blockDim.x + threadIdx.x;
    if (e >= NEDGES) return;
    int tgt = edge_index[e];
    int src = edge_index[NEDGES + e];
    int nt = node_features[tgt];
    int ns = node_features[src];
    int ee = edge_features[e];
    float4 si = s_i_d[nt];
    float4 sj = s_j_d[ns];
    float4 se = s_e_d[ee];
    float4 v;
    v.x = si.x + sj.x + se.x; v.x = v.x > 0.f ? v.x : SLOPE * v.x;
    v.y = si.y + sj.y + se.y; v.y = v.y > 0.f ? v.y : SLOPE * v.y;
    v.z = si.z + sj.z + se.z; v.z = v.z > 0.f ? v.z : SLOPE * v.z;
    v.w = si.w + sj.w + se.w; v.w = v.w > 0.f ? v.w : SLOPE * v.w;
    int pos = atomicAdd(&cursor[tgt], 1);
    csr_eij[pos] = v;
    csr_ns[pos] = ns;
}

// ---- Aggregate: per-node softmax + weighted sum + residual + LayerNorm ----
__global__ __launch_bounds__(128) void node_agg_kernel(
        const int* __restrict__ offsets,
        const float4* __restrict__ csr_eij,
        const int* __restrict__ csr_ns,
        const int* __restrict__ node_features,
        const float* __restrict__ h_dict,
        const float* __restrict__ gamma,
        const float* __restrict__ beta,
        float* __restrict__ out) {
    __shared__ float4 red4[2];
    __shared__ float al[128 * 4];
    __shared__ int nsl[128];
    __shared__ float redln[4];
    int n = blockIdx.x;
    int tid = threadIdx.x;        // = output col
    int h = tid >> 5;
    int off = offsets[n];
    int deg = offsets[n + 1] - off;

    float4 mrun = make_float4(NEG_BIG, NEG_BIG, NEG_BIG, NEG_BIG);
    float4 lrun = make_float4(0.f, 0.f, 0.f, 0.f);
    float acc = 0.f;

    for (int base = 0; base < deg; base += 128) {
        int cnt = min(deg - base, 128);
        float4 ev = make_float4(NEG_BIG, NEG_BIG, NEG_BIG, NEG_BIG);
        int ns = 0;
        if (tid < cnt) {
            ev = csr_eij[off + base + tid];
            ns = csr_ns[off + base + tid];
        }
        // block-wide max of ev per head
        float4 mv = ev;
        #pragma unroll
        for (int o = 32; o > 0; o >>= 1) {
            mv.x = fmaxf(mv.x, __shfl_xor(mv.x, o));
            mv.y = fmaxf(mv.y, __shfl_xor(mv.y, o));
            mv.z = fmaxf(mv.z, __shfl_xor(mv.z, o));
            mv.w = fmaxf(mv.w, __shfl_xor(mv.w, o));
        }
        if ((tid & 63) == 0) red4[tid >> 6] = mv;
        __syncthreads();
        float4 cm;
        cm.x = fmaxf(red4[0].x, red4[1].x);
        cm.y = fmaxf(red4[0].y, red4[1].y);
        cm.z = fmaxf(red4[0].z, red4[1].z);
        cm.w = fmaxf(red4[0].w, red4[1].w);
        float4 newm;
        newm.x = fmaxf(mrun.x, cm.x);
        newm.y = fmaxf(mrun.y, cm.y);
        newm.z = fmaxf(mrun.z, cm.z);
        newm.w = fmaxf(mrun.w, cm.w);
        float4 p = make_float4(0.f, 0.f, 0.f, 0.f);
        if (tid < cnt) {
            p.x = __expf(ev.x - newm.x);
            p.y = __expf(ev.y - newm.y);
            p.z = __expf(ev.z - newm.z);
            p.w = __expf(ev.w - newm.w);
        }
        // block-wide sum of p per head
        float4 sv = p;
        #pragma unroll
        for (int o = 32; o > 0; o >>= 1) {
            sv.x += __shfl_xor(sv.x, o);
            sv.y += __shfl_xor(sv.y, o);
            sv.z += __shfl_xor(sv.z, o);
            sv.w += __shfl_xor(sv.w, o);
        }
        __syncthreads();   // red4 reuse
        if ((tid & 63) == 0) red4[tid >> 6] = sv;
        if (tid < cnt) {
            al[tid * 4 + 0] = p.x; al[tid * 4 + 1] = p.y;
            al[tid * 4 + 2] = p.z; al[tid * 4 + 3] = p.w;
            nsl[tid] = ns;
        }
        __syncthreads();
        float4 cl;
        cl.x = red4[0].x + red4[1].x;
        cl.y = red4[0].y + red4[1].y;
        cl.z = red4[0].z + red4[1].z;
        cl.w = red4[0].w + red4[1].w;
        float4 scale;
        scale.x = __expf(mrun.x - newm.x);
        scale.y = __expf(mrun.y - newm.y);
        scale.z = __expf(mrun.z - newm.z);
        scale.w = __expf(mrun.w - newm.w);
        lrun.x = lrun.x * scale.x + cl.x;
        lrun.y = lrun.y * scale.y + cl.y;
        lrun.z = lrun.z * scale.z + cl.z;
        lrun.w = lrun.w * scale.w + cl.w;
        mrun = newm;
        acc *= (h == 0 ? scale.x : h == 1 ? scale.y : h == 2 ? scale.z : scale.w);
        for (int t = 0; t < cnt; ++t)
            acc += al[t * 4 + h] * h_dict[nsl[t] * DD + tid];
        __syncthreads();   // al/nsl reuse next chunk
    }

    float lh = (h == 0 ? lrun.x : h == 1 ? lrun.y : h == 2 ? lrun.z : lrun.w);
    float msg = lh > 0.f ? acc / lh : 0.f;
    float v = msg + h_dict[node_features[n] * DD + tid];
    // LayerNorm over 128 cols
    float s = v, s2 = v * v;
    #pragma unroll
    for (int o = 32; o > 0; o >>= 1) {
        s  += __shfl_xor(s, o);
        s2 += __shfl_xor(s2, o);
    }
    if ((tid & 63) == 0) { redln[(tid >> 6) * 2] = s; redln[(tid >> 6) * 2 + 1] = s2; }
    __syncthreads();
    s = redln[0] + redln[2];
    s2 = redln[1] + redln[3];
    float mu = s * (1.f / DD);
    float var = s2 * (1.f / DD) - mu * mu;
    float r = rsqrtf(var + LN_EPS);
    out[n * DD + tid] = (v - mu) * r * gamma[tid] + beta[tid];
}

// ---- Edge output: eh2[e] = eh2_dict[edge_features[e]] (float4 gather-write) ----
__global__ void edge_out_kernel(const int* __restrict__ edge_features,
                                const vfloat4* __restrict__ eh2_dict4,
                                vfloat4* __restrict__ out4) {
    int t = blockIdx.x * blockDim.x + threadIdx.x;   // 25.6M threads
    int e = t >> 5;                                  // 32 float4 per row
    int j = t & 31;
    if (e >= NEDGES) return;
    int ee = edge_features[e];
    vfloat4 v = eh2_dict4[ee * 32 + j];
    __builtin_nontemporal_store(v, out4 + (size_t)t);
}

extern "C" void kernel_launch(void* const* d_in, const int* in_sizes, int n_in,
                              void* d_out, int out_size, void* d_ws, size_t ws_size,
                              hipStream_t stream) {
    const int*   node_features = (const int*)d_in[0];
    const int*   edge_features = (const int*)d_in[1];
    const int*   edge_index    = (const int*)d_in[2];
    const float* node_emb      = (const float*)d_in[3];
    const float* edge_emb      = (const float*)d_in[4];
    const float* w_W           = (const float*)d_in[5];
    const float* w_b           = (const float*)d_in[6];
    const float* ew_W          = (const float*)d_in[7];
    const float* ew_b          = (const float*)d_in[8];
    const float* attn          = (const float*)d_in[9];
    const float* gamma         = (const float*)d_in[10];
    const float* beta          = (const float*)d_in[11];

    float* out_nodes = (float*)d_out;                                  // 50000*128
    float* out_edges = (float*)d_out + (size_t)NNODES * DD;            // 800000*128

    // workspace layout (16B-aligned pieces)
    char* w = (char*)d_ws;
    float*  h_dict   = (float*)w;  w += (size_t)NNODE_DICT * DD * 4;   // 5.12 MB
    float*  s_i_d    = (float*)w;  w += (size_t)NNODE_DICT * 4 * 4;    // 160 KB
    float*  s_j_d    = (float*)w;  w += (size_t)NNODE_DICT * 4 * 4;    // 160 KB
    float*  eh2_dict = (float*)w;  w += (size_t)NEDGE_DICT * DD * 4;   // 51 KB
    float*  s_e_d    = (float*)w;  w += (size_t)NEDGE_DICT * 4 * 4;    // 1.6 KB
    int*    counts   = (int*)w;    w += (size_t)NNODES * 4;            // 200 KB
    int*    offsets  = (int*)w;    w += (size_t)(NNODES + 4) * 4;      // 200 KB
    int*    cursor   = (int*)w;    w += (size_t)NNODES * 4;            // 200 KB
    float4* csr_eij  = (float4*)w; w += (size_t)NEDGES * 16;           // 12.8 MB
    int*    csr_ns   = (int*)w;    w += (size_t)NEDGES * 4;            // 3.2 MB

    (void)hipMemsetAsync(counts, 0, (size_t)NNODES * 4, stream);

    node_dict_kernel<<<NNODE_DICT, 128, 0, stream>>>(node_emb, w_W, w_b, attn,
                                                     h_dict, s_i_d, s_j_d);
    edge_dict_kernel<<<NEDGE_DICT, 128, 0, stream>>>(edge_emb, ew_W, ew_b, attn,
                                                     gamma, beta, eh2_dict, s_e_d);
    count_kernel<<<(NEDGES + 255) / 256, 256, 0, stream>>>(edge_index, counts);
    scan_kernel<<<1, 1024, 0, stream>>>(counts, offsets, cursor);
    scatter_kernel<<<(NEDGES + 255) / 256, 256, 0, stream>>>(edge_index, node_features,
                                                             edge_features,
                                                             (const float4*)s_i_d,
                                                             (const float4*)s_j_d,
                                                             (const float4*)s_e_d,
                                                             cursor, csr_eij, csr_ns);
    node_agg_kernel<<<NNODES, 128, 0, stream>>>(offsets, csr_eij, csr_ns,
                                                node_features, h_dict,
                                                gamma, beta, out_nodes);
    edge_out_kernel<<<(NEDGES * 32 + 255) / 256, 256, 0, stream>>>(edge_features,
                                                                   (const vfloat4*)eh2_dict,
                                                                   (vfloat4*)out_edges);
}

// Round 4
// 600.088 us; speedup vs baseline: 1.9690x; 1.1406x over previous
//
#include <hip/hip_runtime.h>

#define NNODES 50000
#define NEDGES 800000
#define NNODE_DICT 10000
#define NEDGE_DICT 100
#define EMB 128
#define HID 32
#define HEADS 4
#define DD 128            // HID*HEADS
#define SLOPE 0.2f
#define LN_EPS 1e-5f
#define NEG_BIG -3.0e38f

typedef float vfloat4 __attribute__((ext_vector_type(4)));

// ---- Kernel A: node dict transform, 4 rows/block, register tiling ----
__global__ __launch_bounds__(128) void node_dict_kernel(
        const float* __restrict__ node_emb,
        const float* __restrict__ w_W,
        const float* __restrict__ w_b,
        const float* __restrict__ attn,
        float* __restrict__ h_dict,
        float* __restrict__ s_i_d,
        float* __restrict__ s_j_d) {
    __shared__ float a_rows[4][EMB];
    int r0 = blockIdx.x * 4;          // 2500 blocks
    int col = threadIdx.x;            // 128 threads
    #pragma unroll
    for (int r = 0; r < 4; ++r) a_rows[r][col] = node_emb[(r0 + r) * EMB + col];
    __syncthreads();
    float acc0 = 0.f, acc1 = 0.f, acc2 = 0.f, acc3 = 0.f;
    #pragma unroll 8
    for (int k = 0; k < EMB; ++k) {
        float wv = w_W[k * DD + col];
        acc0 += a_rows[0][k] * wv;
        acc1 += a_rows[1][k] * wv;
        acc2 += a_rows[2][k] * wv;
        acc3 += a_rows[3][k] * wv;
    }
    float b = w_b[col];
    acc0 += b; acc1 += b; acc2 += b; acc3 += b;
    h_dict[(r0 + 0) * DD + col] = acc0;
    h_dict[(r0 + 1) * DD + col] = acc1;
    h_dict[(r0 + 2) * DD + col] = acc2;
    h_dict[(r0 + 3) * DD + col] = acc3;

    int head = col >> 5, f = col & 31;
    float ai = attn[head * 96 + f];
    float aj = attn[head * 96 + 32 + f];
    float accs[4] = {acc0, acc1, acc2, acc3};
    #pragma unroll
    for (int r = 0; r < 4; ++r) {
        float pi = accs[r] * ai;
        float pj = accs[r] * aj;
        #pragma unroll
        for (int off = 16; off > 0; off >>= 1) {
            pi += __shfl_down(pi, off);
            pj += __shfl_down(pj, off);
        }
        if ((col & 31) == 0) {
            s_i_d[(r0 + r) * HEADS + head] = pi;
            s_j_d[(r0 + r) * HEADS + head] = pj;
        }
    }
}

// ---- Kernel B: edge dict transform + s_e + LayerNorm(eh) per dict row ----
__global__ void edge_dict_kernel(const float* __restrict__ edge_emb,
                                 const float* __restrict__ ew_W,
                                 const float* __restrict__ ew_b,
                                 const float* __restrict__ attn,
                                 const float* __restrict__ gamma,
                                 const float* __restrict__ beta,
                                 float* __restrict__ eh2_dict,
                                 float* __restrict__ s_e_d) {
    __shared__ float a_row[EMB];
    __shared__ float red[4];
    int row = blockIdx.x;
    int col = threadIdx.x;
    a_row[col] = edge_emb[row * EMB + col];
    __syncthreads();
    float acc = 0.f;
    #pragma unroll 8
    for (int k = 0; k < EMB; ++k) acc += a_row[k] * ew_W[k * DD + col];
    acc += ew_b[col];

    int head = col >> 5, f = col & 31;
    float pe = acc * attn[head * 96 + 64 + f];
    #pragma unroll
    for (int off = 16; off > 0; off >>= 1) pe += __shfl_down(pe, off);
    if ((col & 31) == 0) s_e_d[row * HEADS + head] = pe;

    float s = acc, s2 = acc * acc;
    #pragma unroll
    for (int off = 32; off > 0; off >>= 1) {
        s  += __shfl_down(s, off);
        s2 += __shfl_down(s2, off);
    }
    int wid = col >> 6;
    if ((col & 63) == 0) { red[wid * 2] = s; red[wid * 2 + 1] = s2; }
    __syncthreads();
    s = red[0] + red[2];
    s2 = red[1] + red[3];
    float mu = s * (1.f / DD);
    float var = s2 * (1.f / DD) - mu * mu;
    float r = rsqrtf(var + LN_EPS);
    eh2_dict[row * DD + col] = (acc - mu) * r * gamma[col] + beta[col];
}

// ---- CSR step 1: degree count (int4, 4 edges/thread) ----
__global__ void count_kernel(const int* __restrict__ edge_index,
                             int* __restrict__ counts) {
    int i = blockIdx.x * blockDim.x + threadIdx.x;   // 200000 groups
    if (i >= NEDGES / 4) return;
    int4 t = ((const int4*)edge_index)[i];
    atomicAdd(&counts[t.x], 1);
    atomicAdd(&counts[t.y], 1);
    atomicAdd(&counts[t.z], 1);
    atomicAdd(&counts[t.w], 1);
}

// ---- CSR step 2a: per-tile scan (tile = 1024 elems, 256 thr, 4/thread) ----
__global__ __launch_bounds__(256) void scan_tiles(const int* __restrict__ counts,
                                                  int* __restrict__ excl,
                                                  int* __restrict__ tsums) {
    __shared__ int wred[4];
    int tile = blockIdx.x;
    int tid = threadIdx.x;
    int base = tile * 1024 + tid * 4;
    int4 v = make_int4(0, 0, 0, 0);
    if (base + 3 < NNODES) {
        v = *(const int4*)(counts + base);
    } else {
        if (base + 0 < NNODES) v.x = counts[base + 0];
        if (base + 1 < NNODES) v.y = counts[base + 1];
        if (base + 2 < NNODES) v.z = counts[base + 2];
        if (base + 3 < NNODES) v.w = counts[base + 3];
    }
    int tsum = v.x + v.y + v.z + v.w;
    int lane = tid & 63, w = tid >> 6;
    int incl = tsum;
    #pragma unroll
    for (int o = 1; o < 64; o <<= 1) {
        int t = __shfl_up(incl, o);
        if (lane >= o) incl += t;
    }
    if (lane == 63) wred[w] = incl;
    __syncthreads();
    int wexc = 0;
    #pragma unroll
    for (int j = 0; j < 4; ++j) if (j < w) wexc += wred[j];
    int ex = wexc + incl - tsum;
    int4 o4 = make_int4(ex, ex + v.x, ex + v.x + v.y, ex + v.x + v.y + v.z);
    if (base + 3 < NNODES) {
        *(int4*)(excl + base) = o4;
    } else {
        if (base + 0 < NNODES) excl[base + 0] = o4.x;
        if (base + 1 < NNODES) excl[base + 1] = o4.y;
        if (base + 2 < NNODES) excl[base + 2] = o4.z;
        if (base + 3 < NNODES) excl[base + 3] = o4.w;
    }
    if (tid == 255) tsums[tile] = wexc + incl;   // tile total
}

// ---- CSR step 2b: scan the 49 tile sums (one wave) ----
__global__ void scan_sums(int* __restrict__ tsums, int ntiles,
                          int* __restrict__ total) {
    int lane = threadIdx.x;    // 64 threads
    int v = (lane < ntiles) ? tsums[lane] : 0;
    int incl = v;
    #pragma unroll
    for (int o = 1; o < 64; o <<= 1) {
        int t = __shfl_up(incl, o);
        if (lane >= o) incl += t;
    }
    if (lane < ntiles) tsums[lane] = incl - v;   // exclusive
    if (lane == 63) *total = incl;
}

// ---- CSR step 2c: add tile bases, init cursor ----
__global__ void scan_fixup(const int* __restrict__ tsums,
                           int* __restrict__ offsets,
                           int* __restrict__ cursor) {
    int i = blockIdx.x * blockDim.x + threadIdx.x;
    if (i >= NNODES) return;
    int v = offsets[i] + tsums[i >> 10];
    offsets[i] = v;
    cursor[i] = v;
}

// ---- CSR step 3: scatter (ns, ee) into CSR order ----
__global__ void scatter_kernel(const int* __restrict__ edge_index,
                               const int* __restrict__ node_features,
                               const int* __restrict__ edge_features,
                               int* __restrict__ cursor,
                               int2* __restrict__ csr) {
    int e = blockIdx.x * blockDim.x + threadIdx.x;
    if (e >= NEDGES) return;
    int tgt = edge_index[e];
    int src = edge_index[NEDGES + e];
    int ns = node_features[src];
    int ee = edge_features[e];
    int pos = atomicAdd(&cursor[tgt], 1);
    csr[pos] = make_int2(ns, ee);
}

// ---- Aggregate: one wave per node; softmax + weighted sum + residual + LN ----
__global__ __launch_bounds__(256) void node_agg_kernel(
        const int* __restrict__ offsets,
        const int2* __restrict__ csr,
        const int* __restrict__ node_features,
        const float4* __restrict__ s_i4,
        const float4* __restrict__ s_j4,
        const float4* __restrict__ s_e4,
        const float* __restrict__ h_dict,
        const float* __restrict__ gamma,
        const float* __restrict__ beta,
        float* __restrict__ out) {
    __shared__ float sp[4][256];
    __shared__ int   sns[4][64];
    int wid = threadIdx.x >> 6;
    int lane = threadIdx.x & 63;
    int n = blockIdx.x * 4 + wid;
    if (n >= NNODES) return;            // no block barriers below: safe

    int nt = node_features[n];
    float4 si = s_i4[nt];
    int off = offsets[n];
    int deg = offsets[n + 1] - off;

    float m0 = NEG_BIG, m1 = NEG_BIG, m2 = NEG_BIG, m3 = NEG_BIG;
    float l0 = 0.f, l1 = 0.f, l2 = 0.f, l3 = 0.f;
    float acc0 = 0.f, acc1 = 0.f;
    int h0 = lane >> 5;            // head of col=lane      (0/1)
    int h1 = 2 + (lane >> 5);      // head of col=lane+64   (2/3)

    for (int base = 0; base < deg; base += 64) {
        int cnt = min(deg - base, 64);
        float4 ev = make_float4(NEG_BIG, NEG_BIG, NEG_BIG, NEG_BIG);
        int ns = 0;
        if (lane < cnt) {
            int2 pr = csr[off + base + lane];
            ns = pr.x;
            float4 sj = s_j4[pr.x];
            float4 se = s_e4[pr.y];
            ev.x = si.x + sj.x + se.x; ev.x = ev.x > 0.f ? ev.x : SLOPE * ev.x;
            ev.y = si.y + sj.y + se.y; ev.y = ev.y > 0.f ? ev.y : SLOPE * ev.y;
            ev.z = si.z + sj.z + se.z; ev.z = ev.z > 0.f ? ev.z : SLOPE * ev.z;
            ev.w = si.w + sj.w + se.w; ev.w = ev.w > 0.f ? ev.w : SLOPE * ev.w;
        }
        // wave max per head
        float4 mv = ev;
        #pragma unroll
        for (int o = 32; o > 0; o >>= 1) {
            mv.x = fmaxf(mv.x, __shfl_xor(mv.x, o));
            mv.y = fmaxf(mv.y, __shfl_xor(mv.y, o));
            mv.z = fmaxf(mv.z, __shfl_xor(mv.z, o));
            mv.w = fmaxf(mv.w, __shfl_xor(mv.w, o));
        }
        float nm0 = fmaxf(m0, mv.x), nm1 = fmaxf(m1, mv.y);
        float nm2 = fmaxf(m2, mv.z), nm3 = fmaxf(m3, mv.w);
        float4 p = make_float4(0.f, 0.f, 0.f, 0.f);
        if (lane < cnt) {
            p.x = __expf(ev.x - nm0);
            p.y = __expf(ev.y - nm1);
            p.z = __expf(ev.z - nm2);
            p.w = __expf(ev.w - nm3);
        }
        // wave sum per head
        float4 sv = p;
        #pragma unroll
        for (int o = 32; o > 0; o >>= 1) {
            sv.x += __shfl_xor(sv.x, o);
            sv.y += __shfl_xor(sv.y, o);
            sv.z += __shfl_xor(sv.z, o);
            sv.w += __shfl_xor(sv.w, o);
        }
        float sc0 = __expf(m0 - nm0), sc1 = __expf(m1 - nm1);
        float sc2 = __expf(m2 - nm2), sc3 = __expf(m3 - nm3);
        l0 = l0 * sc0 + sv.x; l1 = l1 * sc1 + sv.y;
        l2 = l2 * sc2 + sv.z; l3 = l3 * sc3 + sv.w;
        m0 = nm0; m1 = nm1; m2 = nm2; m3 = nm3;
        acc0 *= (lane < 32) ? sc0 : sc1;
        acc1 *= (lane < 32) ? sc2 : sc3;
        // broadcast p/ns via wave-local LDS (same wave: no barrier needed)
        if (lane < cnt) {
            sp[wid][lane * 4 + 0] = p.x;
            sp[wid][lane * 4 + 1] = p.y;
            sp[wid][lane * 4 + 2] = p.z;
            sp[wid][lane * 4 + 3] = p.w;
            sns[wid][lane] = ns;
        }
        int nst = sns[wid][0];
        for (int t = 0; t < cnt; ++t) {
            const float* hr = h_dict + (size_t)nst * DD;
            float w0 = sp[wid][t * 4 + h0];
            float w1 = sp[wid][t * 4 + h1];
            if (t + 1 < cnt) nst = sns[wid][t + 1];
            acc0 += w0 * hr[lane];
            acc1 += w1 * hr[lane + 64];
        }
    }

    float den0 = (lane < 32) ? l0 : l1;
    float den1 = (lane < 32) ? l2 : l3;
    float msg0 = den0 > 0.f ? acc0 / den0 : 0.f;
    float msg1 = den1 > 0.f ? acc1 / den1 : 0.f;
    const float* hres = h_dict + (size_t)nt * DD;
    float v0 = msg0 + hres[lane];
    float v1 = msg1 + hres[lane + 64];
    // LayerNorm over 128 cols, fully in-wave
    float s = v0 + v1, s2 = v0 * v0 + v1 * v1;
    #pragma unroll
    for (int o = 32; o > 0; o >>= 1) {
        s  += __shfl_xor(s, o);
        s2 += __shfl_xor(s2, o);
    }
    float mu = s * (1.f / DD);
    float var = s2 * (1.f / DD) - mu * mu;
    float r = rsqrtf(var + LN_EPS);
    out[(size_t)n * DD + lane]      = (v0 - mu) * r * gamma[lane] + beta[lane];
    out[(size_t)n * DD + lane + 64] = (v1 - mu) * r * gamma[lane + 64] + beta[lane + 64];
}

// ---- Edge output: eh2[e] = eh2_dict[edge_features[e]] (float4 gather-write) ----
__global__ void edge_out_kernel(const int* __restrict__ edge_features,
                                const vfloat4* __restrict__ eh2_dict4,
                                vfloat4* __restrict__ out4) {
    int t = blockIdx.x * blockDim.x + threadIdx.x;   // 25.6M threads
    int e = t >> 5;                                  // 32 float4 per row
    int j = t & 31;
    if (e >= NEDGES) return;
    int ee = edge_features[e];
    vfloat4 v = eh2_dict4[ee * 32 + j];
    __builtin_nontemporal_store(v, out4 + (size_t)t);
}

extern "C" void kernel_launch(void* const* d_in, const int* in_sizes, int n_in,
                              void* d_out, int out_size, void* d_ws, size_t ws_size,
                              hipStream_t stream) {
    const int*   node_features = (const int*)d_in[0];
    const int*   edge_features = (const int*)d_in[1];
    const int*   edge_index    = (const int*)d_in[2];
    const float* node_emb      = (const float*)d_in[3];
    const float* edge_emb      = (const float*)d_in[4];
    const float* w_W           = (const float*)d_in[5];
    const float* w_b           = (const float*)d_in[6];
    const float* ew_W          = (const float*)d_in[7];
    const float* ew_b          = (const float*)d_in[8];
    const float* attn          = (const float*)d_in[9];
    const float* gamma         = (const float*)d_in[10];
    const float* beta          = (const float*)d_in[11];

    float* out_nodes = (float*)d_out;
    float* out_edges = (float*)d_out + (size_t)NNODES * DD;

    // workspace layout (all pieces 16B-aligned)
    char* w = (char*)d_ws;
    float* h_dict   = (float*)w;  w += (size_t)NNODE_DICT * DD * 4;   // 5.12 MB
    float* s_i_d    = (float*)w;  w += (size_t)NNODE_DICT * 4 * 4;    // 160 KB
    float* s_j_d    = (float*)w;  w += (size_t)NNODE_DICT * 4 * 4;    // 160 KB
    float* eh2_dict = (float*)w;  w += (size_t)NEDGE_DICT * DD * 4;   // 51 KB
    float* s_e_d    = (float*)w;  w += (size_t)NEDGE_DICT * 4 * 4;    // 1.6 KB
    int*   counts   = (int*)w;    w += (size_t)NNODES * 4;            // 200 KB
    int*   offsets  = (int*)w;    w += (size_t)(NNODES + 4) * 4;      // 200 KB
    int*   cursor   = (int*)w;    w += (size_t)NNODES * 4;            // 200 KB
    int*   tsums    = (int*)w;    w += (size_t)64 * 4;                // 256 B
    int2*  csr      = (int2*)w;   w += (size_t)NEDGES * 8;            // 6.4 MB

    const int ntiles = (NNODES + 1023) / 1024;   // 49

    (void)hipMemsetAsync(counts, 0, (size_t)NNODES * 4, stream);

    node_dict_kernel<<<NNODE_DICT / 4, 128, 0, stream>>>(node_emb, w_W, w_b, attn,
                                                         h_dict, s_i_d, s_j_d);
    edge_dict_kernel<<<NEDGE_DICT, 128, 0, stream>>>(edge_emb, ew_W, ew_b, attn,
                                                     gamma, beta, eh2_dict, s_e_d);
    count_kernel<<<(NEDGES / 4 + 255) / 256, 256, 0, stream>>>(edge_index, counts);
    scan_tiles<<<ntiles, 256, 0, stream>>>(counts, offsets, tsums);
    scan_sums<<<1, 64, 0, stream>>>(tsums, ntiles, offsets + NNODES);
    scan_fixup<<<(NNODES + 255) / 256, 256, 0, stream>>>(tsums, offsets, cursor);
    scatter_kernel<<<(NEDGES + 255) / 256, 256, 0, stream>>>(edge_index, node_features,
                                                             edge_features, cursor, csr);
    node_agg_kernel<<<(NNODES + 3) / 4, 256, 0, stream>>>(offsets, csr, node_features,
                                                          (const float4*)s_i_d,
                                                          (const float4*)s_j_d,
                                                          (const float4*)s_e_d,
                                                          h_dict, gamma, beta, out_nodes);
    edge_out_kernel<<<(NEDGES * 32 + 255) / 256, 256, 0, stream>>>(edge_features,
                                                                   (const vfloat4*)eh2_dict,
                                                                   (vfloat4*)out_edges);
}